// Round 2
// baseline (826.632 us; speedup 1.0000x reference)
//
#include <hip/hip_runtime.h>
#include <math.h>

#define DIM 1024
#define HID 4096
#define NE 8
#define NTOK 4096

typedef short s16x8 __attribute__((ext_vector_type(8)));
typedef float f32x4 __attribute__((ext_vector_type(4)));

// fp32 -> bf16 round-to-nearest-even, bit-level
__device__ __forceinline__ unsigned short f2bf(float f) {
  unsigned int u = __float_as_uint(f);
  u = u + 0x7fffu + ((u >> 16) & 1u);
  return (unsigned short)(u >> 16);
}

__device__ __forceinline__ void gll16(const void* g, void* l) {
  __builtin_amdgcn_global_load_lds(
      (const __attribute__((address_space(1))) unsigned int*)g,
      (__attribute__((address_space(3))) unsigned int*)l, 16, 0, 0);
}

// ---------------- zero: d_out + control ints ----------------
__global__ __launch_bounds__(256) void zero_k(float4* out4, int* ctrl) {
  int i = blockIdx.x * 256 + threadIdx.x;
  out4[i] = make_float4(0.f, 0.f, 0.f, 0.f);
  if (i < 32) ctrl[i] = 0;
}

// ---------------- router: logits, top-2, softmax, x->bf16 ----------------
// ctrl[0..8): counts  ctrl[8..17): offsets  ctrl[20..28): cursors
__global__ __launch_bounds__(256) void router_k(const float* __restrict__ x,
    const float* __restrict__ Wr, const float* __restrict__ br,
    short* __restrict__ xbf, int* __restrict__ ctrl,
    int* __restrict__ sel, float* __restrict__ selw) {
  __shared__ float lred[4 * NE];
  int t = blockIdx.x, tid = threadIdx.x;
  const float* xr = x + (size_t)t * DIM;
  float p[NE];
#pragma unroll
  for (int e = 0; e < NE; ++e) p[e] = 0.f;
#pragma unroll
  for (int it = 0; it < DIM / 256; ++it) {
    int d = it * 256 + tid;
    float xv = xr[d];
    xbf[(size_t)t * DIM + d] = (short)f2bf(xv);
#pragma unroll
    for (int e = 0; e < NE; ++e) p[e] += xv * Wr[d * NE + e];
  }
#pragma unroll
  for (int e = 0; e < NE; ++e) {
    float v = p[e];
#pragma unroll
    for (int off = 32; off > 0; off >>= 1) v += __shfl_down(v, off);
    if ((tid & 63) == 0) lred[(tid >> 6) * NE + e] = v;
  }
  __syncthreads();
  if (tid == 0) {
    float lg[NE];
#pragma unroll
    for (int e = 0; e < NE; ++e)
      lg[e] = lred[e] + lred[NE + e] + lred[2 * NE + e] + lred[3 * NE + e] + br[e];
    int b0 = 0; float v0 = lg[0];
    for (int e = 1; e < NE; ++e) if (lg[e] > v0) { v0 = lg[e]; b0 = e; }
    int b1i = -1; float v1 = -3.4e38f;
    for (int e = 0; e < NE; ++e) if (e != b0 && lg[e] > v1) { v1 = lg[e]; b1i = e; }
    float e1 = expf(v1 - v0);
    float inv = 1.f / (1.f + e1);
    sel[t * 2] = b0; sel[t * 2 + 1] = b1i;
    selw[t * 2] = inv; selw[t * 2 + 1] = e1 * inv;
    atomicAdd(&ctrl[b0], 1); atomicAdd(&ctrl[b1i], 1);
  }
}

// ---------------- scan: offsets ----------------
__global__ void scan_k(int* ctrl) {
  if (threadIdx.x == 0) {
    int o = 0;
#pragma unroll
    for (int e = 0; e < NE; ++e) { ctrl[8 + e] = o; o += ctrl[e]; }
    ctrl[16] = o;
  }
}

// ---------------- build: compact per-expert token lists ----------------
__global__ __launch_bounds__(256) void build_k(const int* __restrict__ sel,
    const float* __restrict__ selw, int* ctrl,
    int* __restrict__ slot_tok, float* __restrict__ slot_w) {
  int t = blockIdx.x * 256 + threadIdx.x;
  if (t >= NTOK) return;
#pragma unroll
  for (int k = 0; k < 2; ++k) {
    int e = sel[t * 2 + k];
    int pos = atomicAdd(&ctrl[20 + e], 1);
    int s = ctrl[8 + e] + pos;
    slot_tok[s] = t;
    slot_w[s] = selw[t * 2 + k];
  }
}

// ---------------- GEMM1: h = gelu(gather(x) @ W1 + b1), bf16 out ----------------
// grid (HID/128, NTOK/128, NE), block 256. BM=128 BN=128 BK=32.
__global__ __launch_bounds__(256) void gemm1_k(const short* __restrict__ xbf,
    const float* __restrict__ W1, const float* __restrict__ b1,
    const int* __restrict__ ctrl, const int* __restrict__ slot_tok,
    short* __restrict__ h) {
  int e = blockIdx.z, my = blockIdx.y, bx = blockIdx.x;
  int cnt = ctrl[e];
  if (my * 128 >= cnt) return;
  int slot0 = ctrl[8 + e];
  int tid = threadIdx.x, lane = tid & 63;
  int wv = tid >> 6, wm = wv >> 1, wn = wv & 1;
  __shared__ __attribute__((aligned(16))) short ldsA[128 * 32];
  __shared__ __attribute__((aligned(16))) short ldsB[128 * 40];  // [n][k] pad->40

  // A gather staging: chunk c covers (row=c>>2, 16B col c&3); 2 chunks/thread
  const short* ap[2]; short* la[2];
#pragma unroll
  for (int i = 0; i < 2; ++i) {
    int c = tid + i * 256;
    int row = c >> 2;
    int srow = min(my * 128 + row, cnt - 1);
    int tok = slot_tok[slot0 + srow];
    ap[i] = xbf + (size_t)tok * DIM + (c & 3) * 8;
    la[i] = &ldsA[c * 8];
  }
  // B staging: thread -> (n0, n0+1) x 8 k's
  int n0 = (tid & 63) * 2;
  int kg = tid >> 6;
  const float* bp = W1 + ((size_t)e * DIM + kg * 8) * HID + bx * 128 + n0;
  short* lb0 = &ldsB[(n0) * 40 + kg * 8];
  short* lb1 = &ldsB[(n0 + 1) * 40 + kg * 8];

  f32x4 acc[4][4];
#pragma unroll
  for (int i = 0; i < 4; ++i)
#pragma unroll
    for (int j = 0; j < 4; ++j) acc[i][j] = (f32x4){0.f, 0.f, 0.f, 0.f};

#pragma unroll 2
  for (int kt = 0; kt < DIM / 32; ++kt) {
    float2 fv[8];
#pragma unroll
    for (int kk = 0; kk < 8; ++kk)
      fv[kk] = *(const float2*)&bp[(size_t)kk * HID];
    __syncthreads();  // previous iteration's compute done
    gll16(ap[0], la[0]);
    gll16(ap[1], la[1]);
    s16x8 v0, v1;
#pragma unroll
    for (int kk = 0; kk < 8; ++kk) {
      v0[kk] = (short)f2bf(fv[kk].x);
      v1[kk] = (short)f2bf(fv[kk].y);
    }
    *(s16x8*)lb0 = v0;
    *(s16x8*)lb1 = v1;
    asm volatile("s_waitcnt vmcnt(0)" ::: "memory");
    __syncthreads();  // tiles visible
    s16x8 aF[4], bF[4];
#pragma unroll
    for (int i = 0; i < 4; ++i)
      aF[i] = *(const s16x8*)&ldsA[(wm * 64 + i * 16 + (lane & 15)) * 32 + (lane >> 4) * 8];
#pragma unroll
    for (int j = 0; j < 4; ++j)
      bF[j] = *(const s16x8*)&ldsB[(wn * 64 + j * 16 + (lane & 15)) * 40 + (lane >> 4) * 8];
#pragma unroll
    for (int i = 0; i < 4; ++i)
#pragma unroll
      for (int j = 0; j < 4; ++j)
        acc[i][j] = __builtin_amdgcn_mfma_f32_16x16x32_bf16(aF[i], bF[j], acc[i][j], 0, 0, 0);
    ap[0] += 32; ap[1] += 32; bp += (size_t)32 * HID;
  }
  // epilogue: bias + exact GELU -> bf16 h
#pragma unroll
  for (int i = 0; i < 4; ++i) {
#pragma unroll
    for (int r = 0; r < 4; ++r) {
      int row_l = wm * 64 + i * 16 + (lane >> 4) * 4 + r;
      int grow = my * 128 + row_l;
      if (grow < cnt) {
#pragma unroll
        for (int j = 0; j < 4; ++j) {
          int col = bx * 128 + wn * 64 + j * 16 + (lane & 15);
          float z = acc[i][j][r] + b1[e * HID + col];
          float g = 0.5f * z * (1.f + erff(z * 0.70710678118f));
          h[(size_t)(slot0 + grow) * HID + col] = (short)f2bf(g);
        }
      }
    }
  }
}

// ---------------- GEMM2: out += w * (h @ W2 + b2) ----------------
// grid (DIM/128, NTOK/128, NE), block 256.
__global__ __launch_bounds__(256) void gemm2_k(const short* __restrict__ h,
    const float* __restrict__ W2, const float* __restrict__ b2,
    const int* __restrict__ ctrl, const int* __restrict__ slot_tok,
    const float* __restrict__ slot_w, float* __restrict__ out) {
  int e = blockIdx.z, my = blockIdx.y, bx = blockIdx.x;
  int cnt = ctrl[e];
  if (my * 128 >= cnt) return;
  int slot0 = ctrl[8 + e];
  int tid = threadIdx.x, lane = tid & 63;
  int wv = tid >> 6, wm = wv >> 1, wn = wv & 1;
  __shared__ __attribute__((aligned(16))) short ldsA[128 * 32];
  __shared__ __attribute__((aligned(16))) short ldsB[128 * 40];
  __shared__ int stok[128];
  __shared__ float swt[128];
  if (tid < 128) {
    int srow = min(my * 128 + tid, cnt - 1);
    stok[tid] = slot_tok[slot0 + srow];
    swt[tid] = slot_w[slot0 + srow];
  }
  const short* ap[2]; short* la[2];
#pragma unroll
  for (int i = 0; i < 2; ++i) {
    int c = tid + i * 256;
    int row = c >> 2;
    int srow = min(my * 128 + row, cnt - 1);
    ap[i] = h + (size_t)(slot0 + srow) * HID + (c & 3) * 8;
    la[i] = &ldsA[c * 8];
  }
  int n0 = (tid & 63) * 2;
  int kg = tid >> 6;
  const float* bp = W2 + ((size_t)e * HID + kg * 8) * DIM + bx * 128 + n0;
  short* lb0 = &ldsB[(n0) * 40 + kg * 8];
  short* lb1 = &ldsB[(n0 + 1) * 40 + kg * 8];

  f32x4 acc[4][4];
#pragma unroll
  for (int i = 0; i < 4; ++i)
#pragma unroll
    for (int j = 0; j < 4; ++j) acc[i][j] = (f32x4){0.f, 0.f, 0.f, 0.f};

#pragma unroll 2
  for (int kt = 0; kt < HID / 32; ++kt) {
    float2 fv[8];
#pragma unroll
    for (int kk = 0; kk < 8; ++kk)
      fv[kk] = *(const float2*)&bp[(size_t)kk * DIM];
    __syncthreads();
    gll16(ap[0], la[0]);
    gll16(ap[1], la[1]);
    s16x8 v0, v1;
#pragma unroll
    for (int kk = 0; kk < 8; ++kk) {
      v0[kk] = (short)f2bf(fv[kk].x);
      v1[kk] = (short)f2bf(fv[kk].y);
    }
    *(s16x8*)lb0 = v0;
    *(s16x8*)lb1 = v1;
    asm volatile("s_waitcnt vmcnt(0)" ::: "memory");
    __syncthreads();
    s16x8 aF[4], bF[4];
#pragma unroll
    for (int i = 0; i < 4; ++i)
      aF[i] = *(const s16x8*)&ldsA[(wm * 64 + i * 16 + (lane & 15)) * 32 + (lane >> 4) * 8];
#pragma unroll
    for (int j = 0; j < 4; ++j)
      bF[j] = *(const s16x8*)&ldsB[(wn * 64 + j * 16 + (lane & 15)) * 40 + (lane >> 4) * 8];
#pragma unroll
    for (int i = 0; i < 4; ++i)
#pragma unroll
      for (int j = 0; j < 4; ++j)
        acc[i][j] = __builtin_amdgcn_mfma_f32_16x16x32_bf16(aF[i], bF[j], acc[i][j], 0, 0, 0);
    ap[0] += 32; ap[1] += 32; bp += (size_t)32 * DIM;
  }
#pragma unroll
  for (int i = 0; i < 4; ++i) {
#pragma unroll
    for (int r = 0; r < 4; ++r) {
      int row_l = wm * 64 + i * 16 + (lane >> 4) * 4 + r;
      int grow = my * 128 + row_l;
      if (grow < cnt) {
        int tok = stok[row_l];
        float wrow = swt[row_l];
#pragma unroll
        for (int j = 0; j < 4; ++j) {
          int col = bx * 128 + wn * 64 + j * 16 + (lane & 15);
          float y = acc[i][j][r] + b2[e * DIM + col];
          unsafeAtomicAdd(&out[(size_t)tok * DIM + col], wrow * y);
        }
      }
    }
  }
}

extern "C" void kernel_launch(void* const* d_in, const int* in_sizes, int n_in,
                              void* d_out, int out_size, void* d_ws, size_t ws_size,
                              hipStream_t stream) {
  const float* x  = (const float*)d_in[0];
  const float* Wr = (const float*)d_in[1];
  const float* br = (const float*)d_in[2];
  const float* W1 = (const float*)d_in[3];
  const float* b1 = (const float*)d_in[4];
  const float* W2 = (const float*)d_in[5];
  const float* b2 = (const float*)d_in[6];
  float* out = (float*)d_out;

  char* ws = (char*)d_ws;
  int*   ctrl     = (int*)(ws);                 // 128 B control
  int*   sel      = (int*)(ws + 1024);          // 2*NTOK ints
  float* selw     = (float*)(ws + 33792);       // 2*NTOK floats
  int*   slot_tok = (int*)(ws + 66560);         // 2*NTOK ints
  float* slot_w   = (float*)(ws + 99328);       // 2*NTOK floats
  short* xbf      = (short*)(ws + (1u << 20));  // 8 MB
  short* h        = (short*)(ws + (16u << 20)); // 67 MB (2*NTOK x HID bf16)

  zero_k<<<(NTOK * DIM / 4) / 256, 256, 0, stream>>>((float4*)out, ctrl);
  router_k<<<NTOK, 256, 0, stream>>>(x, Wr, br, xbf, ctrl, sel, selw);
  scan_k<<<1, 64, 0, stream>>>(ctrl);
  build_k<<<NTOK / 256, 256, 0, stream>>>(sel, selw, ctrl, slot_tok, slot_w);
  gemm1_k<<<dim3(HID / 128, NTOK / 128, NE), 256, 0, stream>>>(xbf, W1, b1, ctrl, slot_tok, h);
  gemm2_k<<<dim3(DIM / 128, NTOK / 128, NE), 256, 0, stream>>>(h, W2, b2, ctrl, slot_tok, slot_w, out);
}